// Round 1
// baseline (104.648 us; speedup 1.0000x reference)
//
#include <hip/hip_runtime.h>

// DCNv3 forward. Layout facts (from the reference's view-reshapes):
//   x   : (B=4, H=128, W=128, C=128) fp32, flat — idx = ((b*128+h)*128+w)*128+c
//   out : same layout
//   W_off  (128,72), b_off(72), W_mask(128,36), b_mask(36)
// ws layout: per pixel 108 floats = [72 offsets (g,p,2)][36 mask logits (g,p)]

#define NPIX 65536  // B*H*W

// ---------------- Kernel A: per-pixel linear layers ----------------
// grid 768 = 3 column-groups x 256 pixel-blocks; block 256 (thread = pixel).
// Weight element is wave-uniform -> scalar loads + v_fmac(vacc, s_w, v_x).
__global__ __launch_bounds__(256) void dcn_lin(
    const float* __restrict__ x, const float* __restrict__ Woff,
    const float* __restrict__ boff, const float* __restrict__ Wmask,
    const float* __restrict__ bmask, float* __restrict__ ws) {
  const int jg = blockIdx.x >> 8;  // 0,1: offset cols; 2: mask cols
  const int pix = ((blockIdx.x & 255) << 8) | threadIdx.x;
  const float* W;
  const float* bias;
  int ldw, obase;
  if (jg == 0) {
    W = Woff; bias = boff; ldw = 72; obase = 0;
  } else if (jg == 1) {
    W = Woff + 36; bias = boff + 36; ldw = 72; obase = 36;
  } else {
    W = Wmask; bias = bmask; ldw = 36; obase = 72;
  }

  float acc[36];
#pragma unroll
  for (int j = 0; j < 36; ++j) acc[j] = bias[j];

  const float* xp = x + (size_t)pix * 128;
  for (int c0 = 0; c0 < 128; c0 += 32) {
    float xr[32];
#pragma unroll
    for (int t = 0; t < 8; ++t)
      *(float4*)(xr + 4 * t) = ((const float4*)(xp + c0))[t];
#pragma unroll
    for (int cc = 0; cc < 32; ++cc) {
      const float xc = xr[cc];
      const float* wr = W + (size_t)(c0 + cc) * ldw;
#pragma unroll
      for (int j = 0; j < 36; ++j) acc[j] = fmaf(xc, wr[j], acc[j]);
    }
  }
  float* o = ws + (size_t)pix * 108 + obase;
#pragma unroll
  for (int j = 0; j < 36; ++j) o[j] = acc[j];
}

// ---------------- Kernel B: softmax + bilinear gather ----------------
// grid 8192, block 256: tid -> (q_sub = tid>>5 of 8 pixels, cq = tid&31 ->
// 4 consecutive channels). Gathers are float4, 2 pixels x 512B per wave-inst.
__global__ __launch_bounds__(256) void dcn_samp(
    const float* __restrict__ x, const float* __restrict__ ws,
    float* __restrict__ out) {
  const int q = (blockIdx.x << 3) | (threadIdx.x >> 5);
  const int cq = threadIdx.x & 31;
  const int c = cq << 2;
  const int g = cq >> 3;
  const int b = q >> 14;
  const int h = (q >> 7) & 127;
  const int w = q & 127;
  const float* wsq = ws + (size_t)q * 108;

  // softmax over the group's 9 logits (redundant across the 8-lane octet)
  float lg[9];
  float mx = -1e30f;
#pragma unroll
  for (int p = 0; p < 9; ++p) {
    lg[p] = wsq[72 + g * 9 + p];
    mx = fmaxf(mx, lg[p]);
  }
  float s = 0.f;
#pragma unroll
  for (int p = 0; p < 9; ++p) {
    lg[p] = __expf(lg[p] - mx);
    s += lg[p];
  }
  const float sinv = 1.0f / s;

  const float* xb = x + ((size_t)b << 21) + c;
  float ax = 0.f, ay = 0.f, az = 0.f, aw = 0.f;
#pragma unroll
  for (int p = 0; p < 9; ++p) {
    const float offx = wsq[g * 18 + p * 2];
    const float offy = wsq[g * 18 + p * 2 + 1];
    // padded-coord sample point
    const float px = (float)(w + p / 3) + offx;
    const float py = (float)(h + p % 3) + offy;
    const float fx = floorf(px), fy = floorf(py);
    const float tx = px - fx, ty = py - fy;
    // unpadded coords of the 00 corner
    const int x0 = (int)fx - 1, y0 = (int)fy - 1;
    const float w00 = (1.f - tx) * (1.f - ty);
    const float w10 = tx * (1.f - ty);
    const float w01 = (1.f - tx) * ty;
    const float w11 = tx * ty;
    const float mk = lg[p] * sinv;
    float sx = 0.f, sy = 0.f, sz = 0.f, sw = 0.f;
#define CORNER(XI, YI, WT)                                                    \
  if ((unsigned)(XI) < 128u && (unsigned)(YI) < 128u) {                       \
    const float4 v =                                                          \
        *(const float4*)(xb + ((size_t)(YI) << 14) + ((size_t)(XI) << 7));    \
    sx = fmaf(WT, v.x, sx);                                                   \
    sy = fmaf(WT, v.y, sy);                                                   \
    sz = fmaf(WT, v.z, sz);                                                   \
    sw = fmaf(WT, v.w, sw);                                                   \
  }
    CORNER(x0, y0, w00)
    CORNER(x0 + 1, y0, w10)
    CORNER(x0, y0 + 1, w01)
    CORNER(x0 + 1, y0 + 1, w11)
#undef CORNER
    ax = fmaf(mk, sx, ax);
    ay = fmaf(mk, sy, ay);
    az = fmaf(mk, sz, az);
    aw = fmaf(mk, sw, aw);
  }
  float4 o;
  o.x = ax; o.y = ay; o.z = az; o.w = aw;
  *(float4*)(out + (size_t)q * 128 + c) = o;
}

// ---------------- Fallback: fully fused, one pixel per 128-thread block ----
__global__ __launch_bounds__(128) void dcn_fused(
    const float* __restrict__ x, const float* __restrict__ Woff,
    const float* __restrict__ boff, const float* __restrict__ Wmask,
    const float* __restrict__ bmask, float* __restrict__ out) {
  __shared__ float xs[128];
  __shared__ float res[108];
  __shared__ float msk[36];
  const int q = blockIdx.x;
  const int t = threadIdx.x;
  const int b = q >> 14, h = (q >> 7) & 127, w = q & 127;
  xs[t] = x[(size_t)q * 128 + t];
  __syncthreads();
  if (t < 108) {
    float a;
    const float* W;
    int ld;
    if (t < 72) {
      a = boff[t]; W = Woff + t; ld = 72;
    } else {
      a = bmask[t - 72]; W = Wmask + (t - 72); ld = 36;
    }
    for (int cc = 0; cc < 128; ++cc) a = fmaf(xs[cc], W[(size_t)cc * ld], a);
    res[t] = a;
  }
  __syncthreads();
  if (t < 4) {
    float mx = -1e30f;
    for (int p = 0; p < 9; ++p) mx = fmaxf(mx, res[72 + t * 9 + p]);
    float s = 0.f;
    float e[9];
    for (int p = 0; p < 9; ++p) {
      e[p] = __expf(res[72 + t * 9 + p] - mx);
      s += e[p];
    }
    for (int p = 0; p < 9; ++p) msk[t * 9 + p] = e[p] / s;
  }
  __syncthreads();
  const int g = t >> 5;
  const float* xb = x + ((size_t)b << 21) + t;
  float acc = 0.f;
#pragma unroll
  for (int p = 0; p < 9; ++p) {
    const float offx = res[g * 18 + p * 2];
    const float offy = res[g * 18 + p * 2 + 1];
    const float px = (float)(w + p / 3) + offx;
    const float py = (float)(h + p % 3) + offy;
    const float fx = floorf(px), fy = floorf(py);
    const float tx = px - fx, ty = py - fy;
    const int x0 = (int)fx - 1, y0 = (int)fy - 1;
    float sv = 0.f;
#define CORNER1(XI, YI, WT)                                       \
  if ((unsigned)(XI) < 128u && (unsigned)(YI) < 128u)             \
    sv = fmaf((WT), xb[((size_t)(YI) << 14) + ((size_t)(XI) << 7)], sv);
    CORNER1(x0, y0, (1.f - tx) * (1.f - ty))
    CORNER1(x0 + 1, y0, tx * (1.f - ty))
    CORNER1(x0, y0 + 1, (1.f - tx) * ty)
    CORNER1(x0 + 1, y0 + 1, tx * ty)
#undef CORNER1
    acc = fmaf(msk[g * 9 + p], sv, acc);
  }
  out[(size_t)q * 128 + t] = acc;
}

extern "C" void kernel_launch(void* const* d_in, const int* in_sizes, int n_in,
                              void* d_out, int out_size, void* d_ws,
                              size_t ws_size, hipStream_t stream) {
  const float* x = (const float*)d_in[0];
  const float* Woff = (const float*)d_in[1];
  const float* boff = (const float*)d_in[2];
  const float* Wmask = (const float*)d_in[3];
  const float* bmask = (const float*)d_in[4];
  float* out = (float*)d_out;
  const size_t need = (size_t)NPIX * 108 * sizeof(float);
  if (ws_size >= need) {
    float* ws = (float*)d_ws;
    dcn_lin<<<768, 256, 0, stream>>>(x, Woff, boff, Wmask, bmask, ws);
    dcn_samp<<<8192, 256, 0, stream>>>(x, ws, out);
  } else {
    dcn_fused<<<NPIX, 128, 0, stream>>>(x, Woff, boff, Wmask, bmask, out);
  }
}

// Round 2
// 104.078 us; speedup vs baseline: 1.0055x; 1.0055x over previous
//
#include <hip/hip_runtime.h>

// DCNv3 forward, fp32. Layouts (from the reference's view-reshapes):
//   x   : (B=4, H=128, W=128, C=128) flat — idx = ((b*128+h)*128+w)*128+c
//   out : same
//   W_off (128,72), b_off(72), W_mask(128,36), b_mask(36)
// ws: SoA, ws[j*NPIX + pix]; j<72 = offsets (g,p,2), j in [72,108) = softmaxed
// mask (g,p). SoA makes lin's stores coalesced (256B/lane-row per store inst).

#define NPIX 65536  // B*H*W

// ---------------- Kernel A: per-pixel linear layers + mask softmax ---------
// grid 768 = 3 column-groups x 256 pixel-blocks; block 256 (thread = pixel).
// Weight address is wave-uniform (blockIdx-derived) -> scalar loads expected;
// inner loop is v_fmac(vacc, s_w, v_x).
__global__ __launch_bounds__(256) void dcn_lin(
    const float* __restrict__ x, const float* __restrict__ Woff,
    const float* __restrict__ boff, const float* __restrict__ Wmask,
    const float* __restrict__ bmask, float* __restrict__ ws) {
  const int jg = blockIdx.x >> 8;  // 0,1: offset cols; 2: mask cols
  const int pix = ((blockIdx.x & 255) << 8) | threadIdx.x;
  const float* W;
  const float* bias;
  int ldw, obase;
  if (jg == 0) {
    W = Woff; bias = boff; ldw = 72; obase = 0;
  } else if (jg == 1) {
    W = Woff + 36; bias = boff + 36; ldw = 72; obase = 36;
  } else {
    W = Wmask; bias = bmask; ldw = 36; obase = 72;
  }

  float acc[36];
#pragma unroll
  for (int j = 0; j < 36; ++j) acc[j] = bias[j];

  const float* xp = x + (size_t)pix * 128;
  for (int c0 = 0; c0 < 128; c0 += 8) {
    float xr[8];
    *(float4*)(xr) = *(const float4*)(xp + c0);
    *(float4*)(xr + 4) = *(const float4*)(xp + c0 + 4);
#pragma unroll
    for (int cc = 0; cc < 8; ++cc) {
      const float xc = xr[cc];
      const float* wr = W + (size_t)(c0 + cc) * ldw;
#pragma unroll
      for (int j = 0; j < 36; ++j) acc[j] = fmaf(xc, wr[j], acc[j]);
    }
  }

  if (jg == 2) {
    // softmax over each group's 9 logits
#pragma unroll
    for (int g = 0; g < 4; ++g) {
      float mx = acc[g * 9];
#pragma unroll
      for (int p = 1; p < 9; ++p) mx = fmaxf(mx, acc[g * 9 + p]);
      float s = 0.f;
#pragma unroll
      for (int p = 0; p < 9; ++p) {
        acc[g * 9 + p] = __expf(acc[g * 9 + p] - mx);
        s += acc[g * 9 + p];
      }
      const float sinv = 1.0f / s;
#pragma unroll
      for (int p = 0; p < 9; ++p) acc[g * 9 + p] *= sinv;
    }
  }

#pragma unroll
  for (int j = 0; j < 36; ++j) ws[(size_t)(obase + j) * NPIX + pix] = acc[j];
}

// ---------------- Kernel B: bilinear gather ----------------
// block 256 = 16 pixels x 16 lanes; lane = 8 consecutive channels (g = sub>>2).
// Per-point coord/weight math amortized over 8 channels; corner loads are
// always-executed clamped loads with validity folded into the weights
// (exactly the reference's clip-index + zero-weight semantics).
__global__ __launch_bounds__(256) void dcn_samp(
    const float* __restrict__ x, const float* __restrict__ ws,
    float* __restrict__ out) {
  const int q = (blockIdx.x << 4) | (threadIdx.x >> 4);
  const int sub = threadIdx.x & 15;
  const int c = sub << 3;
  const int g = sub >> 2;
  const int b = q >> 14;
  const int h = (q >> 7) & 127;
  const int w = q & 127;

  const float* xb = x + ((size_t)b << 21) + c;
  const float* wsq = ws + q;

  float a0 = 0.f, a1 = 0.f, a2 = 0.f, a3 = 0.f;
  float a4 = 0.f, a5 = 0.f, a6 = 0.f, a7 = 0.f;
#pragma unroll
  for (int p = 0; p < 9; ++p) {
    const float offx = wsq[(size_t)(g * 18 + p * 2) * NPIX];
    const float offy = wsq[(size_t)(g * 18 + p * 2 + 1) * NPIX];
    const float mk = wsq[(size_t)(72 + g * 9 + p) * NPIX];
    // padded-coord sample point
    const float px = (float)(w + p / 3) + offx;
    const float py = (float)(h + p % 3) + offy;
    const float fx = floorf(px), fy = floorf(py);
    const float tx = px - fx, ty = py - fy;
    // unpadded coords of the 00 corner
    const int x0 = (int)fx - 1, y0 = (int)fy - 1;
    const int x1 = x0 + 1, y1 = y0 + 1;
    // separable validity folded into the 1-D weights
    const float ax0 = ((unsigned)x0 < 128u) ? (1.f - tx) : 0.f;
    const float ax1 = ((unsigned)x1 < 128u) ? tx : 0.f;
    const float ay0 = ((unsigned)y0 < 128u) ? (mk * (1.f - ty)) : 0.f;
    const float ay1 = ((unsigned)y1 < 128u) ? (mk * ty) : 0.f;
    const float w00 = ax0 * ay0, w10 = ax1 * ay0;
    const float w01 = ax0 * ay1, w11 = ax1 * ay1;
    // clamped addresses (weight is zero when clamped)
    const int cx0 = min(max(x0, 0), 127), cy0 = min(max(y0, 0), 127);
    const int cx1 = min(max(x1, 0), 127), cy1 = min(max(y1, 0), 127);
    const int r0 = cy0 << 14, r1 = cy1 << 14;
    const int o00 = r0 | (cx0 << 7), o10 = r0 | (cx1 << 7);
    const int o01 = r1 | (cx0 << 7), o11 = r1 | (cx1 << 7);
    const float4 v00a = *(const float4*)(xb + o00);
    const float4 v00b = *(const float4*)(xb + o00 + 4);
    const float4 v10a = *(const float4*)(xb + o10);
    const float4 v10b = *(const float4*)(xb + o10 + 4);
    const float4 v01a = *(const float4*)(xb + o01);
    const float4 v01b = *(const float4*)(xb + o01 + 4);
    const float4 v11a = *(const float4*)(xb + o11);
    const float4 v11b = *(const float4*)(xb + o11 + 4);
    a0 = fmaf(w00, v00a.x, fmaf(w10, v10a.x, fmaf(w01, v01a.x, fmaf(w11, v11a.x, a0))));
    a1 = fmaf(w00, v00a.y, fmaf(w10, v10a.y, fmaf(w01, v01a.y, fmaf(w11, v11a.y, a1))));
    a2 = fmaf(w00, v00a.z, fmaf(w10, v10a.z, fmaf(w01, v01a.z, fmaf(w11, v11a.z, a2))));
    a3 = fmaf(w00, v00a.w, fmaf(w10, v10a.w, fmaf(w01, v01a.w, fmaf(w11, v11a.w, a3))));
    a4 = fmaf(w00, v00b.x, fmaf(w10, v10b.x, fmaf(w01, v01b.x, fmaf(w11, v11b.x, a4))));
    a5 = fmaf(w00, v00b.y, fmaf(w10, v10b.y, fmaf(w01, v01b.y, fmaf(w11, v11b.y, a5))));
    a6 = fmaf(w00, v00b.z, fmaf(w10, v10b.z, fmaf(w01, v01b.z, fmaf(w11, v11b.z, a6))));
    a7 = fmaf(w00, v00b.w, fmaf(w10, v10b.w, fmaf(w01, v01b.w, fmaf(w11, v11b.w, a7))));
  }
  float4 oa, ob;
  oa.x = a0; oa.y = a1; oa.z = a2; oa.w = a3;
  ob.x = a4; ob.y = a5; ob.z = a6; ob.w = a7;
  float* op = out + (size_t)q * 128 + c;
  *(float4*)op = oa;
  *(float4*)(op + 4) = ob;
}

// ---------------- Fallback: fully fused, one pixel per 128-thread block ----
__global__ __launch_bounds__(128) void dcn_fused(
    const float* __restrict__ x, const float* __restrict__ Woff,
    const float* __restrict__ boff, const float* __restrict__ Wmask,
    const float* __restrict__ bmask, float* __restrict__ out) {
  __shared__ float xs[128];
  __shared__ float res[108];
  __shared__ float msk[36];
  const int q = blockIdx.x;
  const int t = threadIdx.x;
  const int b = q >> 14, h = (q >> 7) & 127, w = q & 127;
  xs[t] = x[(size_t)q * 128 + t];
  __syncthreads();
  if (t < 108) {
    float a;
    const float* W;
    int ld;
    if (t < 72) {
      a = boff[t]; W = Woff + t; ld = 72;
    } else {
      a = bmask[t - 72]; W = Wmask + (t - 72); ld = 36;
    }
    for (int cc = 0; cc < 128; ++cc) a = fmaf(xs[cc], W[(size_t)cc * ld], a);
    res[t] = a;
  }
  __syncthreads();
  if (t < 4) {
    float mx = -1e30f;
    for (int p = 0; p < 9; ++p) mx = fmaxf(mx, res[72 + t * 9 + p]);
    float s = 0.f;
    float e[9];
    for (int p = 0; p < 9; ++p) {
      e[p] = __expf(res[72 + t * 9 + p] - mx);
      s += e[p];
    }
    for (int p = 0; p < 9; ++p) msk[t * 9 + p] = e[p] / s;
  }
  __syncthreads();
  const int g = t >> 5;
  const float* xb = x + ((size_t)b << 21) + t;
  float acc = 0.f;
#pragma unroll
  for (int p = 0; p < 9; ++p) {
    const float offx = res[g * 18 + p * 2];
    const float offy = res[g * 18 + p * 2 + 1];
    const float px = (float)(w + p / 3) + offx;
    const float py = (float)(h + p % 3) + offy;
    const float fx = floorf(px), fy = floorf(py);
    const float tx = px - fx, ty = py - fy;
    const int x0 = (int)fx - 1, y0 = (int)fy - 1;
    float sv = 0.f;
#define CORNER1(XI, YI, WT)                                       \
  if ((unsigned)(XI) < 128u && (unsigned)(YI) < 128u)             \
    sv = fmaf((WT), xb[((size_t)(YI) << 14) + ((size_t)(XI) << 7)], sv);
    CORNER1(x0, y0, (1.f - tx) * (1.f - ty))
    CORNER1(x0 + 1, y0, tx * (1.f - ty))
    CORNER1(x0, y0 + 1, (1.f - tx) * ty)
    CORNER1(x0 + 1, y0 + 1, tx * ty)
#undef CORNER1
    acc = fmaf(msk[g * 9 + p], sv, acc);
  }
  out[(size_t)q * 128 + t] = acc;
}

extern "C" void kernel_launch(void* const* d_in, const int* in_sizes, int n_in,
                              void* d_out, int out_size, void* d_ws,
                              size_t ws_size, hipStream_t stream) {
  const float* x = (const float*)d_in[0];
  const float* Woff = (const float*)d_in[1];
  const float* boff = (const float*)d_in[2];
  const float* Wmask = (const float*)d_in[3];
  const float* bmask = (const float*)d_in[4];
  float* out = (float*)d_out;
  const size_t need = (size_t)NPIX * 108 * sizeof(float);
  if (ws_size >= need) {
    float* ws = (float*)d_ws;
    dcn_lin<<<768, 256, 0, stream>>>(x, Woff, boff, Wmask, bmask, ws);
    dcn_samp<<<4096, 256, 0, stream>>>(x, ws, out);
  } else {
    dcn_fused<<<NPIX, 128, 0, stream>>>(x, Woff, boff, Wmask, bmask, out);
  }
}